// Round 1
// baseline (138.840 us; speedup 1.0000x reference)
//
#include <hip/hip_runtime.h>
#include <hip/hip_fp16.h>
#include <math.h>

#define N_PTS 50000
#define C_DIM 64
#define K_RAD 32
#define K_KNN 10
#define E_RAD (N_PTS * K_RAD)
#define NGRP (N_PTS / 8)              // 6250 node-groups of 8 nodes

// ROCm hip_fp16.h has no __hmax2; emit packed fp16 max directly.
__device__ inline __half2 hmax2(__half2 a, __half2 b) {
    __half2 d;
    asm("v_pk_max_f16 %0, %1, %2" : "=v"(d) : "v"(a), "v"(b));
    return d;
}

__device__ inline __half2 shfl_xor_h2(__half2 v, int mask) {
    int i = *(int*)&v;
    int r = __shfl_xor(i, mask);
    return *(__half2*)&r;
}

// ---------------- K0: pack geo table only ----------------
// geo[i] = 2 x float4 (32 B): {pos0.xyz, x0.x}, {x0.y, x0.z, assign_bits, 0}
__global__ void pack_tables_kernel(const float* __restrict__ pos0,
                                   const float* __restrict__ x0,
                                   const int* __restrict__ assign,
                                   float4* __restrict__ geo) {
    int i = blockIdx.x * blockDim.x + threadIdx.x;
    if (i >= N_PTS) return;
    geo[i * 2 + 0] = make_float4(pos0[3 * i], pos0[3 * i + 1], pos0[3 * i + 2], x0[3 * i]);
    geo[i * 2 + 1] = make_float4(x0[3 * i + 1], x0[3 * i + 2], __int_as_float(assign[i]), 0.0f);
}

// ---------------- K2: fused edge-weight + layer 1 + rt4 pack ----------
// 16 nodes/block (exact: 3125 blocks), 4 nodes/wave, 2 edges/lane.
// m1 written in PLANE layout: m1[plane][node][32ch] (64 B rows) so the
// layer kernels can keep per-XCD gather working-set inside one 4 MiB L2.
// Word 12 of the rt4 row gets (sum1 - 17) for the conf chain.
__global__ void ew_layer1_kernel(const float4* __restrict__ geo,
                                 const float* __restrict__ R0,
                                 const float* __restrict__ t0,
                                 const int* __restrict__ src,
                                 unsigned int* __restrict__ packed,
                                 __half* __restrict__ m1,
                                 float4* __restrict__ rt4) {
    __shared__ int lm[16][C_DIM];     // 4 KB block max array
    __shared__ float ldsR[16 * 9];
    __shared__ float ldsT[16 * 3];
    float* rt4f = (float*)rt4;
    int tid = threadIdx.x;
    int blk = blockIdx.x;
    ((int*)lm)[tid] = 0;
    ((int*)lm)[tid + 256] = 0;
    ((int*)lm)[tid + 512] = 0;
    ((int*)lm)[tid + 768] = 0;
    if (tid < 144) ldsR[tid] = R0[blk * 144 + tid];
    if (tid < 48) ldsT[tid] = t0[blk * 48 + tid];
    int nl = tid >> 4;                // local node 0..15
    int ng = blk * 16 + nl;           // global node
    int e0 = tid & 15, e1 = e0 + 16;
    int s0 = src[ng * K_RAD + e0];
    int s1 = src[ng * K_RAD + e1];
    float4 g0a = geo[s0 * 2 + 0];
    float4 g0b = geo[s0 * 2 + 1];
    float4 g1a = geo[s1 * 2 + 0];
    float4 g1b = geo[s1 * 2 + 1];
    __syncthreads();
    // rt4 pack for this block's 16 nodes (threads 0..47, one float4 each)
    if (tid < 48) {
        int n = tid / 3, slot = tid % 3;
        const float* Rp = ldsR + n * 9;
        const float* Tp = ldsT + n * 3;
        float4 q;
        if (slot == 0) q = make_float4(Rp[0], Rp[1], Rp[2], Rp[3]);
        else if (slot == 1) q = make_float4(Rp[4], Rp[5], Rp[6], Rp[7]);
        else q = make_float4(Rp[8], Tp[0], Tp[1], Tp[2]);
        rt4[(blk * 16 + n) * 4 + slot] = q;
    }
    const float* R = ldsR + nl * 9;
    const float* T = ldsT + nl * 3;
    float r0 = R[0] * g0a.x + R[1] * g0a.y + R[2] * g0a.z + T[0] - g0a.w;
    float r1 = R[3] * g0a.x + R[4] * g0a.y + R[5] * g0a.z + T[1] - g0b.x;
    float r2 = R[6] * g0a.x + R[7] * g0a.y + R[8] * g0a.z + T[2] - g0b.y;
    float d0 = r0 * r0 + r1 * r1 + r2 * r2;
    float w0 = 1.0f / (1.0f + __expf(d0 - 0.01f));
    float u0 = R[0] * g1a.x + R[1] * g1a.y + R[2] * g1a.z + T[0] - g1a.w;
    float u1 = R[3] * g1a.x + R[4] * g1a.y + R[5] * g1a.z + T[1] - g1b.x;
    float u2 = R[6] * g1a.x + R[7] * g1a.y + R[8] * g1a.z + T[2] - g1b.y;
    float d1 = u0 * u0 + u1 * u1 + u2 * u2;
    float w1 = 1.0f / (1.0f + __expf(d1 - 0.01f));
    packed[ng * K_RAD + e0] =
        ((unsigned int)s0 << 16) | (unsigned int)__half_as_ushort(__float2half_rn(w0));
    packed[ng * K_RAD + e1] =
        ((unsigned int)s1 << 16) | (unsigned int)__half_as_ushort(__float2half_rn(w1));
    atomicMax(&lm[nl][__float_as_int(g0b.z)], __float_as_int(w0));
    atomicMax(&lm[nl][__float_as_int(g1b.z)], __float_as_int(w1));
    __syncthreads();
    // m1 + sum1: thread -> node tid>>4, channel quad (tid&15)*4, plane layout
    int c0 = (tid & 15) * 4;
    float v0 = __int_as_float(lm[nl][c0 + 0]);
    float v1 = __int_as_float(lm[nl][c0 + 1]);
    float v2 = __int_as_float(lm[nl][c0 + 2]);
    float v3 = __int_as_float(lm[nl][c0 + 3]);
    __half2 h01 = __floats2half2_rn(v0, v1);
    __half2 h23 = __floats2half2_rn(v2, v3);
    uint2 uo = make_uint2(*(unsigned int*)&h01, *(unsigned int*)&h23);
    int plane = c0 >> 5;
    int ci = c0 & 31;
    *(uint2*)(m1 + plane * (N_PTS * 32) + ng * 32 + ci) = uo;
    float s = v0 + v1 + v2 + v3;
    s += __shfl_down(s, 8);
    s += __shfl_down(s, 4);
    s += __shfl_down(s, 2);
    s += __shfl_down(s, 1);
    if ((tid & 15) == 0) rt4f[ng * 16 + 12] = s - 17.0f;   // sum1 - 17
}

// ---------------- K3: fp16 layer 2, XCD-pinned plane split ----------
// Grid = 12504 blocks. XCD = blockIdx%8 (round-robin dispatch heuristic):
// XCDs 0-3 process plane 0 only, XCDs 4-7 plane 1 only -> per-XCD gather
// working set = 3.2 MB < 4 MiB L2. Worst case (mapping wrong) = status quo.
// Per wave: 2 nodes; per half-wave: 8 eslots x 4 edges, 4 lanes x 16 B/row.
// Partial channel sums -> rt4 words 13 (plane0) / 14 (plane1).
__global__ void layer_pk_kernel(const unsigned int* __restrict__ packed,
                                const __half* __restrict__ xin,
                                __half* __restrict__ xout,
                                float* __restrict__ rt4f) {
    int blk = blockIdx.x;
    int plane = (blk & 7) >> 2;             // xcd 0-3 -> plane0, 4-7 -> plane1
    int grp = (blk >> 3) * 4 + (blk & 3);   // node group (8 nodes)
    if (grp >= NGRP) return;
    int tid = threadIdx.x;
    int lane = tid & 63;
    int node = grp * 8 + (tid >> 6) * 2 + (lane >> 5);
    int hl = lane & 31;
    int eslot = hl >> 2;                    // 0..7
    int cpos = lane & 3;                    // 0..3 -> 8 channels each
    const __half* xp = xin + plane * (N_PTS * 32);
    uint4 pk = *(const uint4*)(packed + node * K_RAD + eslot * 4);
    unsigned int pes[4] = {pk.x, pk.y, pk.z, pk.w};
    float4 f[4];
#pragma unroll
    for (int p = 0; p < 4; ++p)
        f[p] = *(const float4*)(xp + (pes[p] >> 16) * 32 + cpos * 8);
    __half2 a0 = __float2half2_rn(0.0f), a1 = a0, a2 = a0, a3 = a0;
#pragma unroll
    for (int p = 0; p < 4; ++p) {
        __half2* h = (__half2*)&f[p];
        __half2 w2 = __half2half2(__ushort_as_half((unsigned short)(pes[p] & 0xffffu)));
        a0 = hmax2(a0, __hmul2(w2, h[0]));
        a1 = hmax2(a1, __hmul2(w2, h[1]));
        a2 = hmax2(a2, __hmul2(w2, h[2]));
        a3 = hmax2(a3, __hmul2(w2, h[3]));
    }
#pragma unroll
    for (int off = 4; off <= 16; off <<= 1) {   // max across 8 eslots
        a0 = hmax2(a0, shfl_xor_h2(a0, off));
        a1 = hmax2(a1, shfl_xor_h2(a1, off));
        a2 = hmax2(a2, shfl_xor_h2(a2, off));
        a3 = hmax2(a3, shfl_xor_h2(a3, off));
    }
    if (eslot == 0) {
        float4 o;
        __half2* oh = (__half2*)&o;
        oh[0] = a0; oh[1] = a1; oh[2] = a2; oh[3] = a3;
        *(float4*)(xout + plane * (N_PTS * 32) + node * 32 + cpos * 8) = o;
    }
    float2 v0 = __half22float2(a0), v1 = __half22float2(a1);
    float2 v2 = __half22float2(a2), v3 = __half22float2(a3);
    float s = v0.x + v0.y + v1.x + v1.y + v2.x + v2.y + v3.x + v3.y;
    s += __shfl_xor(s, 1);
    s += __shfl_xor(s, 2);
    if (hl == 0) rt4f[node * 16 + 13 + plane] = s;   // s2a / s2b
}

// ---------------- K4: layer 3 partial sums, same XCD plane split --------
// Only channel sums are needed (m3 == m4 == m5). plane0 -> rt4 word 15,
// plane1 -> sum3b[] (no free word left in the row).
__global__ void layer3_partial_kernel(const unsigned int* __restrict__ packed,
                                      const __half* __restrict__ xin,
                                      float* __restrict__ rt4f,
                                      float* __restrict__ sum3b) {
    int blk = blockIdx.x;
    int plane = (blk & 7) >> 2;
    int grp = (blk >> 3) * 4 + (blk & 3);
    if (grp >= NGRP) return;
    int tid = threadIdx.x;
    int lane = tid & 63;
    int node = grp * 8 + (tid >> 6) * 2 + (lane >> 5);
    int hl = lane & 31;
    int eslot = hl >> 2;
    int cpos = lane & 3;
    const __half* xp = xin + plane * (N_PTS * 32);
    uint4 pk = *(const uint4*)(packed + node * K_RAD + eslot * 4);
    unsigned int pes[4] = {pk.x, pk.y, pk.z, pk.w};
    float4 f[4];
#pragma unroll
    for (int p = 0; p < 4; ++p)
        f[p] = *(const float4*)(xp + (pes[p] >> 16) * 32 + cpos * 8);
    __half2 a0 = __float2half2_rn(0.0f), a1 = a0, a2 = a0, a3 = a0;
#pragma unroll
    for (int p = 0; p < 4; ++p) {
        __half2* h = (__half2*)&f[p];
        __half2 w2 = __half2half2(__ushort_as_half((unsigned short)(pes[p] & 0xffffu)));
        a0 = hmax2(a0, __hmul2(w2, h[0]));
        a1 = hmax2(a1, __hmul2(w2, h[1]));
        a2 = hmax2(a2, __hmul2(w2, h[2]));
        a3 = hmax2(a3, __hmul2(w2, h[3]));
    }
#pragma unroll
    for (int off = 4; off <= 16; off <<= 1) {
        a0 = hmax2(a0, shfl_xor_h2(a0, off));
        a1 = hmax2(a1, shfl_xor_h2(a1, off));
        a2 = hmax2(a2, shfl_xor_h2(a2, off));
        a3 = hmax2(a3, shfl_xor_h2(a3, off));
    }
    float2 v0 = __half22float2(a0), v1 = __half22float2(a1);
    float2 v2 = __half22float2(a2), v3 = __half22float2(a3);
    float s = v0.x + v0.y + v1.x + v1.y + v2.x + v2.y + v3.x + v3.y;
    s += __shfl_xor(s, 1);
    s += __shfl_xor(s, 2);
    if (hl == 0) {
        if (plane == 0) rt4f[node * 16 + 15] = s;    // s3a
        else            sum3b[node] = s;             // s3b
    }
}

// ---------------- K4.5: finalize confidence ----------------
// conf = sigmoid((sum1-17) + s2a + s2b + 3*(s3a + s3b)) -> rt4 word 12.
__global__ void conf_kernel(float* __restrict__ rt4f,
                            const float* __restrict__ sum3b) {
    int n = blockIdx.x * blockDim.x + threadIdx.x;
    if (n >= N_PTS) return;
    float4 v = *(const float4*)(rt4f + n * 16 + 12);  // {sum1-17, s2a, s2b, s3a}
    float tot = v.x + v.y + v.z + 3.0f * (v.w + sum3b[n]);
    rt4f[n * 16 + 12] = 1.0f / (1.0f + __expf(-tot));
}

// ---------------- K5: weighted average over knn + rigid transform --------
// 8 lanes per node (two 4-lane halves, 5 edges each). All knn ids and all
// rt4 rows are fetched in two batched epochs (no 10-deep serial chain),
// then halves combine with shfl_xor(4). 6250 waves -> 24/CU.
__global__ void wavg_kernel(const int* __restrict__ knn_src,
                            const float4* __restrict__ rt4,
                            const float* __restrict__ pos0,
                            float* __restrict__ out) {
    int gid = blockIdx.x * blockDim.x + threadIdx.x;
    int lane = gid & 63;
    int t = gid >> 3;
    int part = lane & 3;
    int half = (lane >> 2) & 1;
    if (t >= N_PTS) return;
    int ids[5];
#pragma unroll
    for (int k = 0; k < 5; ++k) ids[k] = knn_src[t * K_KNN + half * 5 + k];
    float4 q[5];
#pragma unroll
    for (int k = 0; k < 5; ++k) q[k] = rt4[ids[k] * 4 + part];
    float4 acc = make_float4(0.f, 0.f, 0.f, 0.f);
#pragma unroll
    for (int k = 0; k < 5; ++k) {
        float c = __shfl(q[k].x, lane | 3);   // part3 row: q.x = conf[s]
        if (part == 3) {
            acc.x += c;
        } else {
            acc.x += c * q[k].x; acc.y += c * q[k].y;
            acc.z += c * q[k].z; acc.w += c * q[k].w;
        }
    }
    // combine the two 5-edge halves
    acc.x += __shfl_xor(acc.x, 4);
    acc.y += __shfl_xor(acc.y, 4);
    acc.z += __shfl_xor(acc.z, 4);
    acc.w += __shfl_xor(acc.w, 4);
    float den = __shfl(acc.x, lane | 3) + 1e-8f;
    float inv = 1.0f / den;
    float4 sc = make_float4(acc.x * inv, acc.y * inv, acc.z * inv, acc.w * inv);
    int base = lane & ~3;
    float R3 = __shfl(sc.w, base + 0);
    float R6 = __shfl(sc.z, base + 1);
    float R7 = __shfl(sc.w, base + 1);
    float t0v = __shfl(sc.y, base + 2);
    float t1v = __shfl(sc.z, base + 2);
    if (half == 0) {
        float px = pos0[t * 3 + 0], py = pos0[t * 3 + 1], pz = pos0[t * 3 + 2];
        float* Rout = out + N_PTS * 3;
        float* tout = out + N_PTS * 12;
        if (part == 0) {
            out[t * 3 + 0] = sc.x * px + sc.y * py + sc.z * pz + t0v;
            Rout[t * 9 + 0] = sc.x; Rout[t * 9 + 1] = sc.y;
            Rout[t * 9 + 2] = sc.z; Rout[t * 9 + 3] = sc.w;
        } else if (part == 1) {
            out[t * 3 + 1] = R3 * px + sc.x * py + sc.y * pz + t1v;
            Rout[t * 9 + 4] = sc.x; Rout[t * 9 + 5] = sc.y;
            Rout[t * 9 + 6] = sc.z; Rout[t * 9 + 7] = sc.w;
        } else if (part == 2) {
            out[t * 3 + 2] = R6 * px + R7 * py + sc.x * pz + sc.w;
            Rout[t * 9 + 8] = sc.x;
            tout[t * 3 + 0] = sc.y; tout[t * 3 + 1] = sc.z; tout[t * 3 + 2] = sc.w;
        }
    }
}

extern "C" void kernel_launch(void* const* d_in, const int* in_sizes, int n_in,
                              void* d_out, int out_size, void* d_ws, size_t ws_size,
                              hipStream_t stream) {
    const float* x0 = (const float*)d_in[0];
    const float* pos0 = (const float*)d_in[1];
    const float* R0 = (const float*)d_in[2];
    const float* t0 = (const float*)d_in[3];
    const int* assign01 = (const int*)d_in[4];
    const int* radius_src = (const int*)d_in[5];
    const int* knn_src = (const int*)d_in[7];

    // All tables 128-B aligned.
    char* ws = (char*)d_ws;
    unsigned int* packed = (unsigned int*)ws;                  // @0          6,400,000 B
    __half* mA = (__half*)(ws + 6400000);                      // @6.4M       6,400,000 B  [2][N][32]
    __half* mB = (__half*)(ws + 12800000);                     // @12.8M      6,400,000 B  [2][N][32]
    float4* geo = (float4*)(ws + 19200000);                    // @19.2M      1,600,000 B
    float4* rt4 = (float4*)(ws + 20800000);                    // @20.8M      3,200,000 B
    float* sum3b = (float*)(ws + 24000000);                    //   200,000 B
    float* out = (float*)d_out;

    pack_tables_kernel<<<(N_PTS + 255) / 256, 256, 0, stream>>>(
        pos0, x0, assign01, geo);

    // 16 nodes/block, exact grid; packs rt4 R/t rows + (sum1-17) into word 12
    ew_layer1_kernel<<<N_PTS / 16, 256, 0, stream>>>(
        geo, R0, t0, radius_src, packed, mA, rt4);

    // XCD-plane-split layer kernels: 1563 octets of blocks, guard inside
    layer_pk_kernel<<<1563 * 8, 256, 0, stream>>>(
        packed, mA, mB, (float*)rt4);

    layer3_partial_kernel<<<1563 * 8, 256, 0, stream>>>(
        packed, mB, (float*)rt4, sum3b);

    conf_kernel<<<(N_PTS + 255) / 256, 256, 0, stream>>>(
        (float*)rt4, sum3b);

    wavg_kernel<<<(N_PTS * 8 + 255) / 256, 256, 0, stream>>>(
        knn_src, rt4, pos0, out);
}

// Round 2
// 138.182 us; speedup vs baseline: 1.0048x; 1.0048x over previous
//
#include <hip/hip_runtime.h>
#include <hip/hip_fp16.h>
#include <math.h>

#define N_PTS 50000
#define C_DIM 64
#define K_RAD 32
#define K_KNN 10

typedef unsigned int uv4 __attribute__((ext_vector_type(4)));
typedef unsigned int uv2 __attribute__((ext_vector_type(2)));

// ROCm hip_fp16.h has no __hmax2; emit packed fp16 max directly.
__device__ inline __half2 hmax2(__half2 a, __half2 b) {
    __half2 d;
    asm("v_pk_max_f16 %0, %1, %2" : "=v"(d) : "v"(a), "v"(b));
    return d;
}

__device__ inline __half2 shfl_xor_h2(__half2 v, int mask) {
    int i = *(int*)&v;
    int r = __shfl_xor(i, mask);
    return *(__half2*)&r;
}

// ---------------- K0: pack geo table ----------------
// geo[i] = 2 x float4 (32 B): {pos0.xyz, x0.x}, {x0.y, x0.z, assign_bits, 0}
// Normal (cached) stores: geo is K2's gather table — leave it L2-warm.
__global__ void pack_tables_kernel(const float* __restrict__ pos0,
                                   const float* __restrict__ x0,
                                   const int* __restrict__ assign,
                                   float4* __restrict__ geo) {
    int i = blockIdx.x * blockDim.x + threadIdx.x;
    if (i >= N_PTS) return;
    geo[i * 2 + 0] = make_float4(pos0[3 * i], pos0[3 * i + 1], pos0[3 * i + 2], x0[3 * i]);
    geo[i * 2 + 1] = make_float4(x0[3 * i + 1], x0[3 * i + 2], __int_as_float(assign[i]), 0.0f);
}

// ---------------- K2: fused edge-weight + layer 1 + rt4 pack ----------
// 16 nodes/block (exact: 3125 blocks), 4 nodes/wave, 2 edges/lane.
// Streams (src reads, packed writes) are non-temporal so they don't evict
// the geo gather table from L2. m1 written with normal stores (it is the
// next kernel's gather table — keep it resident).
// rt4 word 12 gets (sum1 - 17) for the conf chain.
__global__ void ew_layer1_kernel(const float4* __restrict__ geo,
                                 const float* __restrict__ R0,
                                 const float* __restrict__ t0,
                                 const int* __restrict__ src,
                                 unsigned int* __restrict__ packed,
                                 __half* __restrict__ m1,
                                 float4* __restrict__ rt4) {
    __shared__ int lm[16][C_DIM];     // 4 KB block max array
    __shared__ float ldsR[16 * 9];
    __shared__ float ldsT[16 * 3];
    float* rt4f = (float*)rt4;
    int tid = threadIdx.x;
    int blk = blockIdx.x;
    ((int*)lm)[tid] = 0;
    ((int*)lm)[tid + 256] = 0;
    ((int*)lm)[tid + 512] = 0;
    ((int*)lm)[tid + 768] = 0;
    if (tid < 144) ldsR[tid] = R0[blk * 144 + tid];
    if (tid < 48) ldsT[tid] = t0[blk * 48 + tid];
    int nl = tid >> 4;                // local node 0..15
    int ng = blk * 16 + nl;           // global node
    int e0 = tid & 15, e1 = e0 + 16;
    int s0 = __builtin_nontemporal_load(src + ng * K_RAD + e0);
    int s1 = __builtin_nontemporal_load(src + ng * K_RAD + e1);
    float4 g0a = geo[s0 * 2 + 0];
    float4 g0b = geo[s0 * 2 + 1];
    float4 g1a = geo[s1 * 2 + 0];
    float4 g1b = geo[s1 * 2 + 1];
    __syncthreads();
    // rt4 pack for this block's 16 nodes (threads 0..47, one float4 each)
    if (tid < 48) {
        int n = tid / 3, slot = tid % 3;
        const float* Rp = ldsR + n * 9;
        const float* Tp = ldsT + n * 3;
        float4 q;
        if (slot == 0) q = make_float4(Rp[0], Rp[1], Rp[2], Rp[3]);
        else if (slot == 1) q = make_float4(Rp[4], Rp[5], Rp[6], Rp[7]);
        else q = make_float4(Rp[8], Tp[0], Tp[1], Tp[2]);
        rt4[(blk * 16 + n) * 4 + slot] = q;
    }
    const float* R = ldsR + nl * 9;
    const float* T = ldsT + nl * 3;
    float r0 = R[0] * g0a.x + R[1] * g0a.y + R[2] * g0a.z + T[0] - g0a.w;
    float r1 = R[3] * g0a.x + R[4] * g0a.y + R[5] * g0a.z + T[1] - g0b.x;
    float r2 = R[6] * g0a.x + R[7] * g0a.y + R[8] * g0a.z + T[2] - g0b.y;
    float d0 = r0 * r0 + r1 * r1 + r2 * r2;
    float w0 = 1.0f / (1.0f + __expf(d0 - 0.01f));
    float u0 = R[0] * g1a.x + R[1] * g1a.y + R[2] * g1a.z + T[0] - g1a.w;
    float u1 = R[3] * g1a.x + R[4] * g1a.y + R[5] * g1a.z + T[1] - g1b.x;
    float u2 = R[6] * g1a.x + R[7] * g1a.y + R[8] * g1a.z + T[2] - g1b.y;
    float d1 = u0 * u0 + u1 * u1 + u2 * u2;
    float w1 = 1.0f / (1.0f + __expf(d1 - 0.01f));
    unsigned int p0 =
        ((unsigned int)s0 << 16) | (unsigned int)__half_as_ushort(__float2half_rn(w0));
    unsigned int p1 =
        ((unsigned int)s1 << 16) | (unsigned int)__half_as_ushort(__float2half_rn(w1));
    __builtin_nontemporal_store(p0, packed + ng * K_RAD + e0);
    __builtin_nontemporal_store(p1, packed + ng * K_RAD + e1);
    atomicMax(&lm[nl][__float_as_int(g0b.z)], __float_as_int(w0));
    atomicMax(&lm[nl][__float_as_int(g1b.z)], __float_as_int(w1));
    __syncthreads();
    // m1 + sum1: thread -> node tid>>4, channel quad (tid&15)*4
    int c0 = (tid & 15) * 4;
    float v0 = __int_as_float(lm[nl][c0 + 0]);
    float v1 = __int_as_float(lm[nl][c0 + 1]);
    float v2 = __int_as_float(lm[nl][c0 + 2]);
    float v3 = __int_as_float(lm[nl][c0 + 3]);
    __half2 h01 = __floats2half2_rn(v0, v1);
    __half2 h23 = __floats2half2_rn(v2, v3);
    uint2 uo = make_uint2(*(unsigned int*)&h01, *(unsigned int*)&h23);
    *(uint2*)(m1 + ng * C_DIM + c0) = uo;   // normal store: next gather table
    float s = v0 + v1 + v2 + v3;
    s += __shfl_down(s, 8);
    s += __shfl_down(s, 4);
    s += __shfl_down(s, 2);
    s += __shfl_down(s, 1);
    if ((tid & 15) == 0) rt4f[ng * 16 + 12] = s - 17.0f;   // sum1 - 17
}

// ---------------- K3: fp16 layer 2, full 64-ch rows ----------------
// 2 nodes/wave, 8 nodes/block, exact grid (6250 blocks).
// packed reads non-temporal (read-once stream, keep L2 for the m1 table);
// m2 output via normal stores (layer-3's gather table).
// Channel sum -> rt4 word 13.
__global__ void layer2_kernel(const unsigned int* __restrict__ packed,
                              const __half* __restrict__ xin,
                              __half* __restrict__ xout,
                              float* __restrict__ rt4f) {
    int gid = blockIdx.x * blockDim.x + threadIdx.x;
    int lane = gid & 63;
    int node = (gid >> 6) * 2 + (lane >> 5);
    int eslot = (lane >> 3) & 3;
    int cpos = lane & 7;
    const uv4* pk4 = (const uv4*)(packed + node * K_RAD + eslot * 8);
    uv4 q0 = __builtin_nontemporal_load(pk4);
    uv4 q1 = __builtin_nontemporal_load(pk4 + 1);
    unsigned int pes[8] = {q0.x, q0.y, q0.z, q0.w, q1.x, q1.y, q1.z, q1.w};
    float4 f[8];
#pragma unroll
    for (int p = 0; p < 8; ++p)
        f[p] = *(const float4*)(xin + (pes[p] >> 16) * C_DIM + cpos * 8);
    __half2 a0 = __float2half2_rn(0.0f), a1 = a0, a2 = a0, a3 = a0;
#pragma unroll
    for (int p = 0; p < 8; ++p) {
        __half2* h = (__half2*)&f[p];
        __half2 w2 = __half2half2(__ushort_as_half((unsigned short)(pes[p] & 0xffffu)));
        a0 = hmax2(a0, __hmul2(w2, h[0]));
        a1 = hmax2(a1, __hmul2(w2, h[1]));
        a2 = hmax2(a2, __hmul2(w2, h[2]));
        a3 = hmax2(a3, __hmul2(w2, h[3]));
    }
#pragma unroll
    for (int off = 8; off <= 16; off <<= 1) {   // max across 4 eslots
        a0 = hmax2(a0, shfl_xor_h2(a0, off));
        a1 = hmax2(a1, shfl_xor_h2(a1, off));
        a2 = hmax2(a2, shfl_xor_h2(a2, off));
        a3 = hmax2(a3, shfl_xor_h2(a3, off));
    }
    if (eslot == 0) {
        float4 o;
        __half2* oh = (__half2*)&o;
        oh[0] = a0; oh[1] = a1; oh[2] = a2; oh[3] = a3;
        ((float4*)(xout + node * C_DIM))[cpos] = o;   // normal store
    }
    float2 v0 = __half22float2(a0), v1 = __half22float2(a1);
    float2 v2 = __half22float2(a2), v3 = __half22float2(a3);
    float s = v0.x + v0.y + v1.x + v1.y + v2.x + v2.y + v3.x + v3.y;
    s += __shfl_xor(s, 1);
    s += __shfl_xor(s, 2);
    s += __shfl_xor(s, 4);
    if ((lane & 31) == 0) rt4f[node * 16 + 13] = s;       // sum2
}

// ---------------- K4: layer 3 channel-sum + fused confidence ----------
// m3 == m4 == m5  =>  conf = sigmoid((sum1-17) + sum2 + 3*sum3).
// conf written into rt4 word 12 for K5. No m3 table is materialized.
__global__ void layer3_conf_kernel(const unsigned int* __restrict__ packed,
                                   const __half* __restrict__ xin,
                                   float* __restrict__ rt4f) {
    int gid = blockIdx.x * blockDim.x + threadIdx.x;
    int lane = gid & 63;
    int node = (gid >> 6) * 2 + (lane >> 5);
    int eslot = (lane >> 3) & 3;
    int cpos = lane & 7;
    const uv4* pk4 = (const uv4*)(packed + node * K_RAD + eslot * 8);
    uv4 q0 = __builtin_nontemporal_load(pk4);
    uv4 q1 = __builtin_nontemporal_load(pk4 + 1);
    unsigned int pes[8] = {q0.x, q0.y, q0.z, q0.w, q1.x, q1.y, q1.z, q1.w};
    float4 f[8];
#pragma unroll
    for (int p = 0; p < 8; ++p)
        f[p] = *(const float4*)(xin + (pes[p] >> 16) * C_DIM + cpos * 8);
    __half2 a0 = __float2half2_rn(0.0f), a1 = a0, a2 = a0, a3 = a0;
#pragma unroll
    for (int p = 0; p < 8; ++p) {
        __half2* h = (__half2*)&f[p];
        __half2 w2 = __half2half2(__ushort_as_half((unsigned short)(pes[p] & 0xffffu)));
        a0 = hmax2(a0, __hmul2(w2, h[0]));
        a1 = hmax2(a1, __hmul2(w2, h[1]));
        a2 = hmax2(a2, __hmul2(w2, h[2]));
        a3 = hmax2(a3, __hmul2(w2, h[3]));
    }
#pragma unroll
    for (int off = 8; off <= 16; off <<= 1) {
        a0 = hmax2(a0, shfl_xor_h2(a0, off));
        a1 = hmax2(a1, shfl_xor_h2(a1, off));
        a2 = hmax2(a2, shfl_xor_h2(a2, off));
        a3 = hmax2(a3, shfl_xor_h2(a3, off));
    }
    float2 v0 = __half22float2(a0), v1 = __half22float2(a1);
    float2 v2 = __half22float2(a2), v3 = __half22float2(a3);
    float s = v0.x + v0.y + v1.x + v1.y + v2.x + v2.y + v3.x + v3.y;
    s += __shfl_xor(s, 1);
    s += __shfl_xor(s, 2);
    s += __shfl_xor(s, 4);
    if ((lane & 31) == 0) {
        float base = rt4f[node * 16 + 12];   // sum1 - 17
        float s2 = rt4f[node * 16 + 13];
        float tot = base + s2 + 3.0f * s;
        rt4f[node * 16 + 12] = 1.0f / (1.0f + __expf(-tot));
    }
}

// ---------------- K5: weighted average over knn + rigid transform --------
// 8 lanes per node (two 4-lane halves, 5 edges each). All knn ids and all
// rt4 rows fetched in two batched epochs (no 10-deep serial chain), then
// halves combine with shfl_xor(4). knn ids and outputs are non-temporal.
__global__ void wavg_kernel(const int* __restrict__ knn_src,
                            const float4* __restrict__ rt4,
                            const float* __restrict__ pos0,
                            float* __restrict__ out) {
    int gid = blockIdx.x * blockDim.x + threadIdx.x;
    int lane = gid & 63;
    int t = gid >> 3;
    int part = lane & 3;
    int half = (lane >> 2) & 1;
    if (t >= N_PTS) return;
    int ids[5];
#pragma unroll
    for (int k = 0; k < 5; ++k)
        ids[k] = __builtin_nontemporal_load(knn_src + t * K_KNN + half * 5 + k);
    float4 q[5];
#pragma unroll
    for (int k = 0; k < 5; ++k) q[k] = rt4[ids[k] * 4 + part];
    float4 acc = make_float4(0.f, 0.f, 0.f, 0.f);
#pragma unroll
    for (int k = 0; k < 5; ++k) {
        float c = __shfl(q[k].x, lane | 3);   // part3 row: q.x = conf[s]
        if (part == 3) {
            acc.x += c;
        } else {
            acc.x += c * q[k].x; acc.y += c * q[k].y;
            acc.z += c * q[k].z; acc.w += c * q[k].w;
        }
    }
    // combine the two 5-edge halves
    acc.x += __shfl_xor(acc.x, 4);
    acc.y += __shfl_xor(acc.y, 4);
    acc.z += __shfl_xor(acc.z, 4);
    acc.w += __shfl_xor(acc.w, 4);
    float den = __shfl(acc.x, lane | 3) + 1e-8f;
    float inv = 1.0f / den;
    float4 sc = make_float4(acc.x * inv, acc.y * inv, acc.z * inv, acc.w * inv);
    int base = lane & ~3;
    float R3 = __shfl(sc.w, base + 0);
    float R6 = __shfl(sc.z, base + 1);
    float R7 = __shfl(sc.w, base + 1);
    float t0v = __shfl(sc.y, base + 2);
    float t1v = __shfl(sc.z, base + 2);
    if (half == 0) {
        float px = pos0[t * 3 + 0], py = pos0[t * 3 + 1], pz = pos0[t * 3 + 2];
        float* Rout = out + N_PTS * 3;
        float* tout = out + N_PTS * 12;
        if (part == 0) {
            __builtin_nontemporal_store(sc.x * px + sc.y * py + sc.z * pz + t0v, out + t * 3 + 0);
            __builtin_nontemporal_store(sc.x, Rout + t * 9 + 0);
            __builtin_nontemporal_store(sc.y, Rout + t * 9 + 1);
            __builtin_nontemporal_store(sc.z, Rout + t * 9 + 2);
            __builtin_nontemporal_store(sc.w, Rout + t * 9 + 3);
        } else if (part == 1) {
            __builtin_nontemporal_store(R3 * px + sc.x * py + sc.y * pz + t1v, out + t * 3 + 1);
            __builtin_nontemporal_store(sc.x, Rout + t * 9 + 4);
            __builtin_nontemporal_store(sc.y, Rout + t * 9 + 5);
            __builtin_nontemporal_store(sc.z, Rout + t * 9 + 6);
            __builtin_nontemporal_store(sc.w, Rout + t * 9 + 7);
        } else if (part == 2) {
            __builtin_nontemporal_store(R6 * px + R7 * py + sc.x * pz + sc.w, out + t * 3 + 2);
            __builtin_nontemporal_store(sc.x, Rout + t * 9 + 8);
            __builtin_nontemporal_store(sc.y, tout + t * 3 + 0);
            __builtin_nontemporal_store(sc.z, tout + t * 3 + 1);
            __builtin_nontemporal_store(sc.w, tout + t * 3 + 2);
        }
    }
}

extern "C" void kernel_launch(void* const* d_in, const int* in_sizes, int n_in,
                              void* d_out, int out_size, void* d_ws, size_t ws_size,
                              hipStream_t stream) {
    const float* x0 = (const float*)d_in[0];
    const float* pos0 = (const float*)d_in[1];
    const float* R0 = (const float*)d_in[2];
    const float* t0 = (const float*)d_in[3];
    const int* assign01 = (const int*)d_in[4];
    const int* radius_src = (const int*)d_in[5];
    const int* knn_src = (const int*)d_in[7];

    // All tables 128-B aligned.
    char* ws = (char*)d_ws;
    unsigned int* packed = (unsigned int*)ws;                  // @0          6,400,000 B
    __half* mA = (__half*)(ws + 6400000);                      // @6.4M       6,400,000 B  [N][64]
    __half* mB = (__half*)(ws + 12800000);                     // @12.8M      6,400,000 B  [N][64]
    float4* geo = (float4*)(ws + 19200000);                    // @19.2M      1,600,000 B
    float4* rt4 = (float4*)(ws + 20800000);                    // @20.8M      3,200,000 B
    float* out = (float*)d_out;

    pack_tables_kernel<<<(N_PTS + 255) / 256, 256, 0, stream>>>(
        pos0, x0, assign01, geo);

    // 16 nodes/block, exact grid; packs rt4 R/t rows + (sum1-17) into word 12
    ew_layer1_kernel<<<N_PTS / 16, 256, 0, stream>>>(
        geo, R0, t0, radius_src, packed, mA, rt4);

    // 2 nodes/wave, 8 nodes/block, exact grid
    layer2_kernel<<<N_PTS / 8, 256, 0, stream>>>(
        packed, mA, mB, (float*)rt4);

    layer3_conf_kernel<<<N_PTS / 8, 256, 0, stream>>>(
        packed, mB, (float*)rt4);

    wavg_kernel<<<(N_PTS * 8 + 255) / 256, 256, 0, stream>>>(
        knn_src, rt4, pos0, out);
}

// Round 3
// 136.659 us; speedup vs baseline: 1.0160x; 1.0111x over previous
//
#include <hip/hip_runtime.h>
#include <hip/hip_fp16.h>
#include <math.h>

#define N_PTS 50000
#define C_DIM 64
#define K_RAD 32
#define K_KNN 10

typedef unsigned int uv4 __attribute__((ext_vector_type(4)));

// ROCm hip_fp16.h has no __hmax2; emit packed fp16 max directly.
__device__ inline __half2 hmax2(__half2 a, __half2 b) {
    __half2 d;
    asm("v_pk_max_f16 %0, %1, %2" : "=v"(d) : "v"(a), "v"(b));
    return d;
}

__device__ inline __half2 shfl_xor_h2(__half2 v, int mask) {
    int i = *(int*)&v;
    int r = __shfl_xor(i, mask);
    return *(__half2*)&r;
}

// ---------------- K0: pack geo table ----------------
// geo[i] = 2 x float4 (32 B): {pos0.xyz, x0.x}, {x0.y, x0.z, assign_bits, 0}
__global__ void pack_tables_kernel(const float* __restrict__ pos0,
                                   const float* __restrict__ x0,
                                   const int* __restrict__ assign,
                                   float4* __restrict__ geo) {
    int i = blockIdx.x * blockDim.x + threadIdx.x;
    if (i >= N_PTS) return;
    geo[i * 2 + 0] = make_float4(pos0[3 * i], pos0[3 * i + 1], pos0[3 * i + 2], x0[3 * i]);
    geo[i * 2 + 1] = make_float4(x0[3 * i + 1], x0[3 * i + 2], __int_as_float(assign[i]), 0.0f);
}

// ---------------- K2: fused edge-weight + layer 1 + rt4 pack ----------
// 16 nodes/block (exact: 3125 blocks), 4 nodes/wave, 2 edges/lane.
// Round-0 memory semantics (no nt hints). rt4 word 12 gets (sum1 - 17).
__global__ void ew_layer1_kernel(const float4* __restrict__ geo,
                                 const float* __restrict__ R0,
                                 const float* __restrict__ t0,
                                 const int* __restrict__ src,
                                 unsigned int* __restrict__ packed,
                                 __half* __restrict__ m1,
                                 float4* __restrict__ rt4) {
    __shared__ int lm[16][C_DIM];     // 4 KB block max array
    __shared__ float ldsR[16 * 9];
    __shared__ float ldsT[16 * 3];
    float* rt4f = (float*)rt4;
    int tid = threadIdx.x;
    int blk = blockIdx.x;
    ((int*)lm)[tid] = 0;
    ((int*)lm)[tid + 256] = 0;
    ((int*)lm)[tid + 512] = 0;
    ((int*)lm)[tid + 768] = 0;
    if (tid < 144) ldsR[tid] = R0[blk * 144 + tid];
    if (tid < 48) ldsT[tid] = t0[blk * 48 + tid];
    int nl = tid >> 4;                // local node 0..15
    int ng = blk * 16 + nl;           // global node
    int e0 = tid & 15, e1 = e0 + 16;
    int s0 = src[ng * K_RAD + e0];
    int s1 = src[ng * K_RAD + e1];
    float4 g0a = geo[s0 * 2 + 0];
    float4 g0b = geo[s0 * 2 + 1];
    float4 g1a = geo[s1 * 2 + 0];
    float4 g1b = geo[s1 * 2 + 1];
    __syncthreads();
    // rt4 pack for this block's 16 nodes (threads 0..47, one float4 each)
    if (tid < 48) {
        int n = tid / 3, slot = tid % 3;
        const float* Rp = ldsR + n * 9;
        const float* Tp = ldsT + n * 3;
        float4 q;
        if (slot == 0) q = make_float4(Rp[0], Rp[1], Rp[2], Rp[3]);
        else if (slot == 1) q = make_float4(Rp[4], Rp[5], Rp[6], Rp[7]);
        else q = make_float4(Rp[8], Tp[0], Tp[1], Tp[2]);
        rt4[(blk * 16 + n) * 4 + slot] = q;
    }
    const float* R = ldsR + nl * 9;
    const float* T = ldsT + nl * 3;
    float r0 = R[0] * g0a.x + R[1] * g0a.y + R[2] * g0a.z + T[0] - g0a.w;
    float r1 = R[3] * g0a.x + R[4] * g0a.y + R[5] * g0a.z + T[1] - g0b.x;
    float r2 = R[6] * g0a.x + R[7] * g0a.y + R[8] * g0a.z + T[2] - g0b.y;
    float d0 = r0 * r0 + r1 * r1 + r2 * r2;
    float w0 = 1.0f / (1.0f + __expf(d0 - 0.01f));
    float u0 = R[0] * g1a.x + R[1] * g1a.y + R[2] * g1a.z + T[0] - g1a.w;
    float u1 = R[3] * g1a.x + R[4] * g1a.y + R[5] * g1a.z + T[1] - g1b.x;
    float u2 = R[6] * g1a.x + R[7] * g1a.y + R[8] * g1a.z + T[2] - g1b.y;
    float d1 = u0 * u0 + u1 * u1 + u2 * u2;
    float w1 = 1.0f / (1.0f + __expf(d1 - 0.01f));
    packed[ng * K_RAD + e0] =
        ((unsigned int)s0 << 16) | (unsigned int)__half_as_ushort(__float2half_rn(w0));
    packed[ng * K_RAD + e1] =
        ((unsigned int)s1 << 16) | (unsigned int)__half_as_ushort(__float2half_rn(w1));
    atomicMax(&lm[nl][__float_as_int(g0b.z)], __float_as_int(w0));
    atomicMax(&lm[nl][__float_as_int(g1b.z)], __float_as_int(w1));
    __syncthreads();
    // m1 + sum1: thread -> node tid>>4, channel quad (tid&15)*4
    int c0 = (tid & 15) * 4;
    float v0 = __int_as_float(lm[nl][c0 + 0]);
    float v1 = __int_as_float(lm[nl][c0 + 1]);
    float v2 = __int_as_float(lm[nl][c0 + 2]);
    float v3 = __int_as_float(lm[nl][c0 + 3]);
    __half2 h01 = __floats2half2_rn(v0, v1);
    __half2 h23 = __floats2half2_rn(v2, v3);
    uint2 uo = make_uint2(*(unsigned int*)&h01, *(unsigned int*)&h23);
    *(uint2*)(m1 + ng * C_DIM + c0) = uo;
    float s = v0 + v1 + v2 + v3;
    s += __shfl_down(s, 8);
    s += __shfl_down(s, 4);
    s += __shfl_down(s, 2);
    s += __shfl_down(s, 1);
    if ((tid & 15) == 0) rt4f[ng * 16 + 12] = s - 17.0f;   // sum1 - 17
}

// ---------------- K3: fp16 layer 2, 1 node/WAVE (occupancy/MLP fix) ------
// lane = eslot*8 + cpos (eslot 0..7 = 4-edge slot, cpos 0..7 = 16B chunk).
// Only f[4] (16 VGPR) staged per lane -> ~50 VGPR -> 8 waves/SIMD via
// __launch_bounds__. 50000 waves total. Channel sum -> rt4 word 13.
__global__ __launch_bounds__(256, 8)
void layer2_kernel(const unsigned int* __restrict__ packed,
                   const __half* __restrict__ xin,
                   __half* __restrict__ xout,
                   float* __restrict__ rt4f) {
    int gid = blockIdx.x * blockDim.x + threadIdx.x;
    int lane = gid & 63;
    int node = gid >> 6;              // 1 node per wave, exact: 50000 waves
    int eslot = lane >> 3;            // 0..7
    int cpos = lane & 7;              // 0..7
    uv4 pk = *(const uv4*)(packed + node * K_RAD + eslot * 4);
    unsigned int pes[4] = {pk.x, pk.y, pk.z, pk.w};
    float4 f[4];
#pragma unroll
    for (int p = 0; p < 4; ++p)
        f[p] = *(const float4*)(xin + (pes[p] >> 16) * C_DIM + cpos * 8);
    __half2 a0 = __float2half2_rn(0.0f), a1 = a0, a2 = a0, a3 = a0;
#pragma unroll
    for (int p = 0; p < 4; ++p) {
        __half2* h = (__half2*)&f[p];
        __half2 w2 = __half2half2(__ushort_as_half((unsigned short)(pes[p] & 0xffffu)));
        a0 = hmax2(a0, __hmul2(w2, h[0]));
        a1 = hmax2(a1, __hmul2(w2, h[1]));
        a2 = hmax2(a2, __hmul2(w2, h[2]));
        a3 = hmax2(a3, __hmul2(w2, h[3]));
    }
#pragma unroll
    for (int off = 8; off <= 32; off <<= 1) {   // max across 8 eslots
        a0 = hmax2(a0, shfl_xor_h2(a0, off));
        a1 = hmax2(a1, shfl_xor_h2(a1, off));
        a2 = hmax2(a2, shfl_xor_h2(a2, off));
        a3 = hmax2(a3, shfl_xor_h2(a3, off));
    }
    if (eslot == 0) {                 // lanes 0..7 write the 128-B row
        float4 o;
        __half2* oh = (__half2*)&o;
        oh[0] = a0; oh[1] = a1; oh[2] = a2; oh[3] = a3;
        ((float4*)(xout + node * C_DIM))[cpos] = o;
    }
    float2 v0 = __half22float2(a0), v1 = __half22float2(a1);
    float2 v2 = __half22float2(a2), v3 = __half22float2(a3);
    float s = v0.x + v0.y + v1.x + v1.y + v2.x + v2.y + v3.x + v3.y;
    s += __shfl_xor(s, 1);
    s += __shfl_xor(s, 2);
    s += __shfl_xor(s, 4);
    if (lane == 0) rt4f[node * 16 + 13] = s;    // sum2
}

// ---------------- K4: layer 3 channel-sum + fused confidence ----------
// Same 1-node/wave structure. m3 == m4 == m5 =>
// conf = sigmoid((sum1-17) + sum2 + 3*sum3) -> rt4 word 12.
__global__ __launch_bounds__(256, 8)
void layer3_conf_kernel(const unsigned int* __restrict__ packed,
                        const __half* __restrict__ xin,
                        float* __restrict__ rt4f) {
    int gid = blockIdx.x * blockDim.x + threadIdx.x;
    int lane = gid & 63;
    int node = gid >> 6;
    int eslot = lane >> 3;
    int cpos = lane & 7;
    uv4 pk = *(const uv4*)(packed + node * K_RAD + eslot * 4);
    unsigned int pes[4] = {pk.x, pk.y, pk.z, pk.w};
    float4 f[4];
#pragma unroll
    for (int p = 0; p < 4; ++p)
        f[p] = *(const float4*)(xin + (pes[p] >> 16) * C_DIM + cpos * 8);
    __half2 a0 = __float2half2_rn(0.0f), a1 = a0, a2 = a0, a3 = a0;
#pragma unroll
    for (int p = 0; p < 4; ++p) {
        __half2* h = (__half2*)&f[p];
        __half2 w2 = __half2half2(__ushort_as_half((unsigned short)(pes[p] & 0xffffu)));
        a0 = hmax2(a0, __hmul2(w2, h[0]));
        a1 = hmax2(a1, __hmul2(w2, h[1]));
        a2 = hmax2(a2, __hmul2(w2, h[2]));
        a3 = hmax2(a3, __hmul2(w2, h[3]));
    }
#pragma unroll
    for (int off = 8; off <= 32; off <<= 1) {
        a0 = hmax2(a0, shfl_xor_h2(a0, off));
        a1 = hmax2(a1, shfl_xor_h2(a1, off));
        a2 = hmax2(a2, shfl_xor_h2(a2, off));
        a3 = hmax2(a3, shfl_xor_h2(a3, off));
    }
    float2 v0 = __half22float2(a0), v1 = __half22float2(a1);
    float2 v2 = __half22float2(a2), v3 = __half22float2(a3);
    float s = v0.x + v0.y + v1.x + v1.y + v2.x + v2.y + v3.x + v3.y;
    s += __shfl_xor(s, 1);
    s += __shfl_xor(s, 2);
    s += __shfl_xor(s, 4);
    if (lane == 0) {
        float base = rt4f[node * 16 + 12];   // sum1 - 17
        float s2 = rt4f[node * 16 + 13];
        float tot = base + s2 + 3.0f * s;
        rt4f[node * 16 + 12] = 1.0f / (1.0f + __expf(-tot));
    }
}

// ---------------- K5: weighted average over knn + rigid transform --------
// 8 lanes per node (two 4-lane halves, 5 edges each). All knn ids and all
// rt4 rows fetched in two batched epochs, halves combine with shfl_xor(4).
__global__ void wavg_kernel(const int* __restrict__ knn_src,
                            const float4* __restrict__ rt4,
                            const float* __restrict__ pos0,
                            float* __restrict__ out) {
    int gid = blockIdx.x * blockDim.x + threadIdx.x;
    int lane = gid & 63;
    int t = gid >> 3;
    int part = lane & 3;
    int half = (lane >> 2) & 1;
    if (t >= N_PTS) return;
    int ids[5];
#pragma unroll
    for (int k = 0; k < 5; ++k) ids[k] = knn_src[t * K_KNN + half * 5 + k];
    float4 q[5];
#pragma unroll
    for (int k = 0; k < 5; ++k) q[k] = rt4[ids[k] * 4 + part];
    float4 acc = make_float4(0.f, 0.f, 0.f, 0.f);
#pragma unroll
    for (int k = 0; k < 5; ++k) {
        float c = __shfl(q[k].x, lane | 3);   // part3 row: q.x = conf[s]
        if (part == 3) {
            acc.x += c;
        } else {
            acc.x += c * q[k].x; acc.y += c * q[k].y;
            acc.z += c * q[k].z; acc.w += c * q[k].w;
        }
    }
    acc.x += __shfl_xor(acc.x, 4);
    acc.y += __shfl_xor(acc.y, 4);
    acc.z += __shfl_xor(acc.z, 4);
    acc.w += __shfl_xor(acc.w, 4);
    float den = __shfl(acc.x, lane | 3) + 1e-8f;
    float inv = 1.0f / den;
    float4 sc = make_float4(acc.x * inv, acc.y * inv, acc.z * inv, acc.w * inv);
    int base = lane & ~3;
    float R3 = __shfl(sc.w, base + 0);
    float R6 = __shfl(sc.z, base + 1);
    float R7 = __shfl(sc.w, base + 1);
    float t0v = __shfl(sc.y, base + 2);
    float t1v = __shfl(sc.z, base + 2);
    if (half == 0) {
        float px = pos0[t * 3 + 0], py = pos0[t * 3 + 1], pz = pos0[t * 3 + 2];
        float* Rout = out + N_PTS * 3;
        float* tout = out + N_PTS * 12;
        if (part == 0) {
            out[t * 3 + 0] = sc.x * px + sc.y * py + sc.z * pz + t0v;
            Rout[t * 9 + 0] = sc.x; Rout[t * 9 + 1] = sc.y;
            Rout[t * 9 + 2] = sc.z; Rout[t * 9 + 3] = sc.w;
        } else if (part == 1) {
            out[t * 3 + 1] = R3 * px + sc.x * py + sc.y * pz + t1v;
            Rout[t * 9 + 4] = sc.x; Rout[t * 9 + 5] = sc.y;
            Rout[t * 9 + 6] = sc.z; Rout[t * 9 + 7] = sc.w;
        } else if (part == 2) {
            out[t * 3 + 2] = R6 * px + R7 * py + sc.x * pz + sc.w;
            Rout[t * 9 + 8] = sc.x;
            tout[t * 3 + 0] = sc.y; tout[t * 3 + 1] = sc.z; tout[t * 3 + 2] = sc.w;
        }
    }
}

extern "C" void kernel_launch(void* const* d_in, const int* in_sizes, int n_in,
                              void* d_out, int out_size, void* d_ws, size_t ws_size,
                              hipStream_t stream) {
    const float* x0 = (const float*)d_in[0];
    const float* pos0 = (const float*)d_in[1];
    const float* R0 = (const float*)d_in[2];
    const float* t0 = (const float*)d_in[3];
    const int* assign01 = (const int*)d_in[4];
    const int* radius_src = (const int*)d_in[5];
    const int* knn_src = (const int*)d_in[7];

    // All tables 128-B aligned.
    char* ws = (char*)d_ws;
    unsigned int* packed = (unsigned int*)ws;                  // @0          6,400,000 B
    __half* mA = (__half*)(ws + 6400000);                      // @6.4M       6,400,000 B  [N][64]
    __half* mB = (__half*)(ws + 12800000);                     // @12.8M      6,400,000 B  [N][64]
    float4* geo = (float4*)(ws + 19200000);                    // @19.2M      1,600,000 B
    float4* rt4 = (float4*)(ws + 20800000);                    // @20.8M      3,200,000 B
    float* out = (float*)d_out;

    pack_tables_kernel<<<(N_PTS + 255) / 256, 256, 0, stream>>>(
        pos0, x0, assign01, geo);

    // 16 nodes/block, exact grid; packs rt4 R/t rows + (sum1-17) into word 12
    ew_layer1_kernel<<<N_PTS / 16, 256, 0, stream>>>(
        geo, R0, t0, radius_src, packed, mA, rt4);

    // 1 node/wave, 4 waves/block, exact grid (12500 blocks)
    layer2_kernel<<<N_PTS / 4, 256, 0, stream>>>(
        packed, mA, mB, (float*)rt4);

    layer3_conf_kernel<<<N_PTS / 4, 256, 0, stream>>>(
        packed, mB, (float*)rt4);

    wavg_kernel<<<(N_PTS * 8 + 255) / 256, 256, 0, stream>>>(
        knn_src, rt4, pos0, out);
}

// Round 5
// 136.099 us; speedup vs baseline: 1.0201x; 1.0041x over previous
//
#include <hip/hip_runtime.h>
#include <hip/hip_fp16.h>
#include <math.h>

#define N_PTS 50000
#define C_DIM 64
#define K_RAD 32
#define K_KNN 10

typedef unsigned int uv4 __attribute__((ext_vector_type(4)));

// ROCm hip_fp16.h has no __hmax2; emit packed fp16 max directly.
__device__ inline __half2 hmax2(__half2 a, __half2 b) {
    __half2 d;
    asm("v_pk_max_f16 %0, %1, %2" : "=v"(d) : "v"(a), "v"(b));
    return d;
}

__device__ inline __half2 shfl_xor_h2(__half2 v, int mask) {
    int i = *(int*)&v;
    int r = __shfl_xor(i, mask);
    return *(__half2*)&r;
}

// ---------------- K0: pack geo table ----------------
// geo[i] = 2 x float4 (32 B): {pos0.xyz, x0.x}, {x0.y, x0.z, assign_bits, 0}
__global__ void pack_tables_kernel(const float* __restrict__ pos0,
                                   const float* __restrict__ x0,
                                   const int* __restrict__ assign,
                                   float4* __restrict__ geo) {
    int i = blockIdx.x * blockDim.x + threadIdx.x;
    if (i >= N_PTS) return;
    geo[i * 2 + 0] = make_float4(pos0[3 * i], pos0[3 * i + 1], pos0[3 * i + 2], x0[3 * i]);
    geo[i * 2 + 1] = make_float4(x0[3 * i + 1], x0[3 * i + 2], __int_as_float(assign[i]), 0.0f);
}

// ---------------- K2: fused edge-weight + layer 1 + rt4 pack ----------
// 16 nodes/block (exact: 3125 blocks), 4 nodes/wave, 2 edges/lane.
// rt4 word 12 gets (sum1 - 17) for the conf chain.
__global__ void ew_layer1_kernel(const float4* __restrict__ geo,
                                 const float* __restrict__ R0,
                                 const float* __restrict__ t0,
                                 const int* __restrict__ src,
                                 unsigned int* __restrict__ packed,
                                 __half* __restrict__ m1,
                                 float4* __restrict__ rt4) {
    __shared__ int lm[16][C_DIM];     // 4 KB block max array
    __shared__ float ldsR[16 * 9];
    __shared__ float ldsT[16 * 3];
    float* rt4f = (float*)rt4;
    int tid = threadIdx.x;
    int blk = blockIdx.x;
    ((int*)lm)[tid] = 0;
    ((int*)lm)[tid + 256] = 0;
    ((int*)lm)[tid + 512] = 0;
    ((int*)lm)[tid + 768] = 0;
    if (tid < 144) ldsR[tid] = R0[blk * 144 + tid];
    if (tid < 48) ldsT[tid] = t0[blk * 48 + tid];
    int nl = tid >> 4;                // local node 0..15
    int ng = blk * 16 + nl;           // global node
    int e0 = tid & 15, e1 = e0 + 16;
    int s0 = src[ng * K_RAD + e0];
    int s1 = src[ng * K_RAD + e1];
    float4 g0a = geo[s0 * 2 + 0];
    float4 g0b = geo[s0 * 2 + 1];
    float4 g1a = geo[s1 * 2 + 0];
    float4 g1b = geo[s1 * 2 + 1];
    __syncthreads();
    // rt4 pack for this block's 16 nodes (threads 0..47, one float4 each)
    if (tid < 48) {
        int n = tid / 3, slot = tid % 3;
        const float* Rp = ldsR + n * 9;
        const float* Tp = ldsT + n * 3;
        float4 q;
        if (slot == 0) q = make_float4(Rp[0], Rp[1], Rp[2], Rp[3]);
        else if (slot == 1) q = make_float4(Rp[4], Rp[5], Rp[6], Rp[7]);
        else q = make_float4(Rp[8], Tp[0], Tp[1], Tp[2]);
        rt4[(blk * 16 + n) * 4 + slot] = q;
    }
    const float* R = ldsR + nl * 9;
    const float* T = ldsT + nl * 3;
    float r0 = R[0] * g0a.x + R[1] * g0a.y + R[2] * g0a.z + T[0] - g0a.w;
    float r1 = R[3] * g0a.x + R[4] * g0a.y + R[5] * g0a.z + T[1] - g0b.x;
    float r2 = R[6] * g0a.x + R[7] * g0a.y + R[8] * g0a.z + T[2] - g0b.y;
    float d0 = r0 * r0 + r1 * r1 + r2 * r2;
    float w0 = 1.0f / (1.0f + __expf(d0 - 0.01f));
    float u0 = R[0] * g1a.x + R[1] * g1a.y + R[2] * g1a.z + T[0] - g1a.w;
    float u1 = R[3] * g1a.x + R[4] * g1a.y + R[5] * g1a.z + T[1] - g1b.x;
    float u2 = R[6] * g1a.x + R[7] * g1a.y + R[8] * g1a.z + T[2] - g1b.y;
    float d1 = u0 * u0 + u1 * u1 + u2 * u2;
    float w1 = 1.0f / (1.0f + __expf(d1 - 0.01f));
    packed[ng * K_RAD + e0] =
        ((unsigned int)s0 << 16) | (unsigned int)__half_as_ushort(__float2half_rn(w0));
    packed[ng * K_RAD + e1] =
        ((unsigned int)s1 << 16) | (unsigned int)__half_as_ushort(__float2half_rn(w1));
    atomicMax(&lm[nl][__float_as_int(g0b.z)], __float_as_int(w0));
    atomicMax(&lm[nl][__float_as_int(g1b.z)], __float_as_int(w1));
    __syncthreads();
    // m1 + sum1: thread -> node tid>>4, channel quad (tid&15)*4
    int c0 = (tid & 15) * 4;
    float v0 = __int_as_float(lm[nl][c0 + 0]);
    float v1 = __int_as_float(lm[nl][c0 + 1]);
    float v2 = __int_as_float(lm[nl][c0 + 2]);
    float v3 = __int_as_float(lm[nl][c0 + 3]);
    __half2 h01 = __floats2half2_rn(v0, v1);
    __half2 h23 = __floats2half2_rn(v2, v3);
    uint2 uo = make_uint2(*(unsigned int*)&h01, *(unsigned int*)&h23);
    *(uint2*)(m1 + ng * C_DIM + c0) = uo;
    float s = v0 + v1 + v2 + v3;
    s += __shfl_down(s, 8);
    s += __shfl_down(s, 4);
    s += __shfl_down(s, 2);
    s += __shfl_down(s, 1);
    if ((tid & 15) == 0) rt4f[ng * 16 + 12] = s - 17.0f;   // sum1 - 17
}

// ---------------- K3: fp16 layer 2, 1 node/wave ----------------
// lane = eslot*8 + cpos (eslot 0..7 = 4-edge slot, cpos 0..7 = 16B chunk).
// f[4] (16 VGPR) staged per lane -> 8 waves/SIMD via __launch_bounds__.
// Channel sum -> rt4 word 13.
__global__ __launch_bounds__(256, 8)
void layer2_kernel(const unsigned int* __restrict__ packed,
                   const __half* __restrict__ xin,
                   __half* __restrict__ xout,
                   float* __restrict__ rt4f) {
    int gid = blockIdx.x * blockDim.x + threadIdx.x;
    int lane = gid & 63;
    int node = gid >> 6;              // 1 node per wave, exact: 50000 waves
    int eslot = lane >> 3;            // 0..7
    int cpos = lane & 7;              // 0..7
    uv4 pk = *(const uv4*)(packed + node * K_RAD + eslot * 4);
    unsigned int pes[4] = {pk.x, pk.y, pk.z, pk.w};
    float4 f[4];
#pragma unroll
    for (int p = 0; p < 4; ++p)
        f[p] = *(const float4*)(xin + (pes[p] >> 16) * C_DIM + cpos * 8);
    __half2 a0 = __float2half2_rn(0.0f), a1 = a0, a2 = a0, a3 = a0;
#pragma unroll
    for (int p = 0; p < 4; ++p) {
        __half2* h = (__half2*)&f[p];
        __half2 w2 = __half2half2(__ushort_as_half((unsigned short)(pes[p] & 0xffffu)));
        a0 = hmax2(a0, __hmul2(w2, h[0]));
        a1 = hmax2(a1, __hmul2(w2, h[1]));
        a2 = hmax2(a2, __hmul2(w2, h[2]));
        a3 = hmax2(a3, __hmul2(w2, h[3]));
    }
#pragma unroll
    for (int off = 8; off <= 32; off <<= 1) {   // max across 8 eslots
        a0 = hmax2(a0, shfl_xor_h2(a0, off));
        a1 = hmax2(a1, shfl_xor_h2(a1, off));
        a2 = hmax2(a2, shfl_xor_h2(a2, off));
        a3 = hmax2(a3, shfl_xor_h2(a3, off));
    }
    if (eslot == 0) {                 // lanes 0..7 write the 128-B row
        float4 o;
        __half2* oh = (__half2*)&o;
        oh[0] = a0; oh[1] = a1; oh[2] = a2; oh[3] = a3;
        ((float4*)(xout + node * C_DIM))[cpos] = o;
    }
    float2 v0 = __half22float2(a0), v1 = __half22float2(a1);
    float2 v2 = __half22float2(a2), v3 = __half22float2(a3);
    float s = v0.x + v0.y + v1.x + v1.y + v2.x + v2.y + v3.x + v3.y;
    s += __shfl_xor(s, 1);
    s += __shfl_xor(s, 2);
    s += __shfl_xor(s, 4);
    if (lane == 0) rt4f[node * 16 + 13] = s;    // sum2
}

// ---------------- K4: layer 3 channel-sum + fused confidence ----------
// Same 1-node/wave structure. m3 == m4 == m5 =>
// conf = sigmoid((sum1-17) + sum2 + 3*sum3) -> rt4 word 12.
__global__ __launch_bounds__(256, 8)
void layer3_conf_kernel(const unsigned int* __restrict__ packed,
                        const __half* __restrict__ xin,
                        float* __restrict__ rt4f) {
    int gid = blockIdx.x * blockDim.x + threadIdx.x;
    int lane = gid & 63;
    int node = gid >> 6;
    int eslot = lane >> 3;
    int cpos = lane & 7;
    uv4 pk = *(const uv4*)(packed + node * K_RAD + eslot * 4);
    unsigned int pes[4] = {pk.x, pk.y, pk.z, pk.w};
    float4 f[4];
#pragma unroll
    for (int p = 0; p < 4; ++p)
        f[p] = *(const float4*)(xin + (pes[p] >> 16) * C_DIM + cpos * 8);
    __half2 a0 = __float2half2_rn(0.0f), a1 = a0, a2 = a0, a3 = a0;
#pragma unroll
    for (int p = 0; p < 4; ++p) {
        __half2* h = (__half2*)&f[p];
        __half2 w2 = __half2half2(__ushort_as_half((unsigned short)(pes[p] & 0xffffu)));
        a0 = hmax2(a0, __hmul2(w2, h[0]));
        a1 = hmax2(a1, __hmul2(w2, h[1]));
        a2 = hmax2(a2, __hmul2(w2, h[2]));
        a3 = hmax2(a3, __hmul2(w2, h[3]));
    }
#pragma unroll
    for (int off = 8; off <= 32; off <<= 1) {
        a0 = hmax2(a0, shfl_xor_h2(a0, off));
        a1 = hmax2(a1, shfl_xor_h2(a1, off));
        a2 = hmax2(a2, shfl_xor_h2(a2, off));
        a3 = hmax2(a3, shfl_xor_h2(a3, off));
    }
    float2 v0 = __half22float2(a0), v1 = __half22float2(a1);
    float2 v2 = __half22float2(a2), v3 = __half22float2(a3);
    float s = v0.x + v0.y + v1.x + v1.y + v2.x + v2.y + v3.x + v3.y;
    s += __shfl_xor(s, 1);
    s += __shfl_xor(s, 2);
    s += __shfl_xor(s, 4);
    if (lane == 0) {
        float base = rt4f[node * 16 + 12];   // sum1 - 17
        float s2 = rt4f[node * 16 + 13];
        float tot = base + s2 + 3.0f * s;
        rt4f[node * 16 + 12] = 1.0f / (1.0f + __expf(-tot));
    }
}

// ---------------- K5: weighted average over knn + rigid transform --------
// 8 lanes per node (two 4-lane halves, 5 edges each). All knn ids and all
// rt4 rows fetched in two batched epochs, halves combine with shfl_xor(4).
__global__ void wavg_kernel(const int* __restrict__ knn_src,
                            const float4* __restrict__ rt4,
                            const float* __restrict__ pos0,
                            float* __restrict__ out) {
    int gid = blockIdx.x * blockDim.x + threadIdx.x;
    int lane = gid & 63;
    int t = gid >> 3;
    int part = lane & 3;
    int half = (lane >> 2) & 1;
    if (t >= N_PTS) return;
    int ids[5];
#pragma unroll
    for (int k = 0; k < 5; ++k) ids[k] = knn_src[t * K_KNN + half * 5 + k];
    float4 q[5];
#pragma unroll
    for (int k = 0; k < 5; ++k) q[k] = rt4[ids[k] * 4 + part];
    float4 acc = make_float4(0.f, 0.f, 0.f, 0.f);
#pragma unroll
    for (int k = 0; k < 5; ++k) {
        float c = __shfl(q[k].x, lane | 3);   // part3 row: q.x = conf[s]
        if (part == 3) {
            acc.x += c;
        } else {
            acc.x += c * q[k].x; acc.y += c * q[k].y;
            acc.z += c * q[k].z; acc.w += c * q[k].w;
        }
    }
    acc.x += __shfl_xor(acc.x, 4);
    acc.y += __shfl_xor(acc.y, 4);
    acc.z += __shfl_xor(acc.z, 4);
    acc.w += __shfl_xor(acc.w, 4);
    float den = __shfl(acc.x, lane | 3) + 1e-8f;
    float inv = 1.0f / den;
    float4 sc = make_float4(acc.x * inv, acc.y * inv, acc.z * inv, acc.w * inv);
    int base = lane & ~3;
    float R3 = __shfl(sc.w, base + 0);
    float R6 = __shfl(sc.z, base + 1);
    float R7 = __shfl(sc.w, base + 1);
    float t0v = __shfl(sc.y, base + 2);
    float t1v = __shfl(sc.z, base + 2);
    if (half == 0) {
        float px = pos0[t * 3 + 0], py = pos0[t * 3 + 1], pz = pos0[t * 3 + 2];
        float* Rout = out + N_PTS * 3;
        float* tout = out + N_PTS * 12;
        if (part == 0) {
            out[t * 3 + 0] = sc.x * px + sc.y * py + sc.z * pz + t0v;
            Rout[t * 9 + 0] = sc.x; Rout[t * 9 + 1] = sc.y;
            Rout[t * 9 + 2] = sc.z; Rout[t * 9 + 3] = sc.w;
        } else if (part == 1) {
            out[t * 3 + 1] = R3 * px + sc.x * py + sc.y * pz + t1v;
            Rout[t * 9 + 4] = sc.x; Rout[t * 9 + 5] = sc.y;
            Rout[t * 9 + 6] = sc.z; Rout[t * 9 + 7] = sc.w;
        } else if (part == 2) {
            out[t * 3 + 2] = R6 * px + R7 * py + sc.x * pz + sc.w;
            Rout[t * 9 + 8] = sc.x;
            tout[t * 3 + 0] = sc.y; tout[t * 3 + 1] = sc.z; tout[t * 3 + 2] = sc.w;
        }
    }
}

extern "C" void kernel_launch(void* const* d_in, const int* in_sizes, int n_in,
                              void* d_out, int out_size, void* d_ws, size_t ws_size,
                              hipStream_t stream) {
    const float* x0 = (const float*)d_in[0];
    const float* pos0 = (const float*)d_in[1];
    const float* R0 = (const float*)d_in[2];
    const float* t0 = (const float*)d_in[3];
    const int* assign01 = (const int*)d_in[4];
    const int* radius_src = (const int*)d_in[5];
    const int* knn_src = (const int*)d_in[7];

    // All tables 128-B aligned.
    char* ws = (char*)d_ws;
    unsigned int* packed = (unsigned int*)ws;                  // @0          6,400,000 B
    __half* mA = (__half*)(ws + 6400000);                      // @6.4M       6,400,000 B  [N][64]
    __half* mB = (__half*)(ws + 12800000);                     // @12.8M      6,400,000 B  [N][64]
    float4* geo = (float4*)(ws + 19200000);                    // @19.2M      1,600,000 B
    float4* rt4 = (float4*)(ws + 20800000);                    // @20.8M      3,200,000 B
    float* out = (float*)d_out;

    pack_tables_kernel<<<(N_PTS + 255) / 256, 256, 0, stream>>>(
        pos0, x0, assign01, geo);

    // 16 nodes/block, exact grid; packs rt4 R/t rows + (sum1-17) into word 12
    ew_layer1_kernel<<<N_PTS / 16, 256, 0, stream>>>(
        geo, R0, t0, radius_src, packed, mA, rt4);

    // 1 node/wave, 4 waves/block, exact grid (12500 blocks)
    layer2_kernel<<<N_PTS / 4, 256, 0, stream>>>(
        packed, mA, mB, (float*)rt4);

    layer3_conf_kernel<<<N_PTS / 4, 256, 0, stream>>>(
        packed, mB, (float*)rt4);

    wavg_kernel<<<(N_PTS * 8 + 255) / 256, 256, 0, stream>>>(
        knn_src, rt4, pos0, out);
}